// Round 10
// baseline (47.533 us; speedup 1.0000x reference)
//
#include <hip/hip_runtime.h>

typedef float v4f __attribute__((ext_vector_type(4)));

#define BLK 256
#define IPT 2                 // i-particles per thread
#define TI (BLK * IPT)        // 512 i's per block
#define TJ 64                 // j's per block
#define JBT (TI / TJ)         // 8 j-blocks per i-tile
#define G_CONST 0.001f
#define EPS_CONST 1e-6f

// Prep: per (b,j) write {-2x,-2y,-2z,|q|^2} SoA into ws so the main kernel can
// s_load j-data into SGPRs (wave-uniform addresses -> scalar pipe, zero LDS).
__global__ void prep_kernel(const float* __restrict__ q, float* __restrict__ jd,
                            int N, int B) {
  const int idx = blockIdx.x * blockDim.x + threadIdx.x;
  if (idx >= B * N) return;
  const int b = idx / N, j = idx - b * N;
  const float x = q[(size_t)b * N * 3 + 3 * j + 0];
  const float y = q[(size_t)b * N * 3 + 3 * j + 1];
  const float z = q[(size_t)b * N * 3 + 3 * j + 2];
  float* base = jd + (size_t)b * 4 * N;
  base[0 * N + j] = -2.f * x;
  base[1 * N + j] = -2.f * y;
  base[2 * N + j] = -2.f * z;
  base[3 * N + j] = fmaf(x, x, fmaf(y, y, z * z));
}

// Triangular at (512 x 64) granularity: 62.5% of full work. Expansion form:
// r^2 = (si+eps) + sj + xi*(-2xj) + yi*(-2yj) + zi*(-2zj).
// All j-operands are SGPRs (s_load from uniform addresses); inner loop has
// zero vector-memory/LDS ops -> pure VALU+trans issue.
template<bool PREP>
__global__ __launch_bounds__(BLK, 4)
void grav_kernel(const float* __restrict__ q, const float* __restrict__ m,
                 const float* __restrict__ jd, float* __restrict__ out, int N) {
  const int b   = blockIdx.z;
  const int tid = threadIdx.x;

  // Decode blockIdx.x -> (i-tile a, j-block jt); i-tile a owns JBT*(a+1) blocks.
  int rel = blockIdx.x;
  int a = 0;
  while (rel >= JBT * (a + 1)) { rel -= JBT * (a + 1); ++a; }
  const int jt   = rel;
  const bool diag = (jt >= JBT * a);
  const int i0 = a * TI;
  const int j0 = jt * TJ;

  __shared__ float wsum[4];

  const float* qb = q + (size_t)b * N * 3;

  float xi[IPT], yi[IPT], zi[IPT], se[IPT], mi[IPT];
#pragma unroll
  for (int s = 0; s < IPT; ++s) {
    const int i = i0 + s * BLK + tid;
    xi[s] = qb[3 * i + 0];
    yi[s] = qb[3 * i + 1];
    zi[s] = qb[3 * i + 2];
    se[s] = fmaf(xi[s], xi[s], fmaf(yi[s], yi[s], fmaf(zi[s], zi[s], EPS_CONST)));
    mi[s] = m[i];
  }

  const float* txp = jd + ((size_t)b * 4 + 0) * N;
  const float* typ = jd + ((size_t)b * 4 + 1) * N;
  const float* tzp = jd + ((size_t)b * 4 + 2) * N;
  const float* sjp = jd + ((size_t)b * 4 + 3) * N;

  float acc[IPT] = {};

#pragma unroll 2
  for (int k = j0; k < j0 + TJ; k += 4) {
    v4f txv, tyv, tzv, sjv;
    const v4f mjv = *(const v4f*)&m[k];          // uniform -> s_load_dwordx4
    if (PREP) {
      txv = *(const v4f*)&txp[k];
      tyv = *(const v4f*)&typ[k];
      tzv = *(const v4f*)&tzp[k];
      sjv = *(const v4f*)&sjp[k];
    } else {
      // Fallback (ws too small): rebuild j-data from q (uniform loads + VALU).
      const v4f q0 = *(const v4f*)&qb[3 * k + 0];   // x0 y0 z0 x1
      const v4f q1 = *(const v4f*)&qb[3 * k + 4];   // y1 z1 x2 y2
      const v4f q2 = *(const v4f*)&qb[3 * k + 8];   // z2 x3 y3 z3
      const v4f xj = {q0.x, q0.w, q1.z, q2.y};
      const v4f yj = {q0.y, q1.x, q1.w, q2.z};
      const v4f zj = {q0.z, q1.y, q2.x, q2.w};
      txv = -2.f * xj; tyv = -2.f * yj; tzv = -2.f * zj;
      sjv = xj * xj + yj * yj + zj * zj;
    }

    if (diag) {
#pragma unroll
      for (int s = 0; s < IPT; ++s) {
        const int i = i0 + s * BLK + tid;
#pragma unroll
        for (int u = 0; u < 4; ++u) {
          float t = se[s] + sjv[u];
          t = fmaf(xi[s], txv[u], t);
          t = fmaf(yi[s], tyv[u], t);
          t = fmaf(zi[s], tzv[u], t);
          float ri = __builtin_amdgcn_rsqf(t);
          ri = (i == k + u) ? 0.f : ri;   // self pair (t may be <=0 -> NaN; masked)
          acc[s] = fmaf(mjv[u], ri, acc[s]);
        }
      }
    } else {
#pragma unroll
      for (int s = 0; s < IPT; ++s) {
#pragma unroll
        for (int u = 0; u < 4; ++u) {
          float t = se[s] + sjv[u];
          t = fmaf(xi[s], txv[u], t);
          t = fmaf(yi[s], tyv[u], t);
          t = fmaf(zi[s], tzv[u], t);
          acc[s] = fmaf(mjv[u], __builtin_amdgcn_rsqf(t), acc[s]);
        }
      }
    }
  }

  float tsum = 0.f;
#pragma unroll
  for (int s = 0; s < IPT; ++s) tsum += mi[s] * acc[s];

  // Block reduction: 64-lane shuffle, then across 4 waves via LDS.
#pragma unroll
  for (int off = 32; off > 0; off >>= 1) tsum += __shfl_down(tsum, off);
  const int wid  = tid >> 6;
  const int lane = tid & 63;
  if (lane == 0) wsum[wid] = tsum;
  __syncthreads();
  if (tid == 0) {
    const float s = (wsum[0] + wsum[1]) + (wsum[2] + wsum[3]);
    // off-diag: each unordered pair once -> -G; diag: both orders -> -G/2.
    const float scale = diag ? (-0.5f * G_CONST) : (-G_CONST);
    atomicAdd(out + b, s * scale);
  }
}

extern "C" void kernel_launch(void* const* d_in, const int* in_sizes, int n_in,
                              void* d_out, int out_size, void* d_ws, size_t ws_size,
                              hipStream_t stream) {
  const float* q = (const float*)d_in[0];
  const float* m = (const float*)d_in[1];
  float* out = (float*)d_out;

  const int N = in_sizes[1];
  const int B = in_sizes[0] / (N * 3);

  hipMemsetAsync(out, 0, (size_t)out_size * sizeof(float), stream);

  const int nti = N / TI;                      // 8 i-tiles
  const int bpb = JBT * nti * (nti + 1) / 2;   // 288 blocks per batch
  dim3 grid(bpb, 1, B);                        // 2304 blocks

  const size_t need = (size_t)B * 4 * N * sizeof(float);   // 512 KB
  if (ws_size >= need) {
    float* jd = (float*)d_ws;
    prep_kernel<<<(B * N + 255) / 256, 256, 0, stream>>>(q, jd, N, B);
    grav_kernel<true><<<grid, BLK, 0, stream>>>(q, m, jd, out, N);
  } else {
    grav_kernel<false><<<grid, BLK, 0, stream>>>(q, m, nullptr, out, N);
  }
}

// Round 11
// 31.316 us; speedup vs baseline: 1.5179x; 1.5179x over previous
//
#include <hip/hip_runtime.h>

typedef float v4f __attribute__((ext_vector_type(4)));

#define BLK 256
#define IPT 4                 // i-particles per thread
#define TI (BLK * IPT)        // 1024 i's per block
#define TJ 64                 // j's staged per block
#define JBT (TI / TJ)         // 16 j-blocks per i-tile
#define G_CONST 0.001f
#define EPS_CONST 1e-6f

// Triangular at (1024 x 64) granularity: 62.5% of full-N^2 work.
// Grid = 1280 blocks with bounds(256,5) -> exactly 5 resident blocks/CU,
// single dispatch round (R9's regression was a 1-block/CU tail round).
// Off-diag: expansion form r^2 = (si+eps+sj) + (-2xi)*xj + (-2yi)*yj + (-2zi)*zj
//   (6 VALU + 1 rsq per pair; -2 folded into per-thread i registers).
// Diag: diff form (7 VALU), self-term cancelled bit-exactly via mi*rsq(EPS).
__global__ __launch_bounds__(BLK, 5)
void grav_kernel(const float* __restrict__ q, const float* __restrict__ m,
                 float* __restrict__ out, int N) {
  const int b   = blockIdx.z;
  const int tid = threadIdx.x;

  // Decode blockIdx.x -> (i-tile a, j-block jt); i-tile a owns JBT*(a+1) blocks.
  int rel = blockIdx.x;
  int a = 0;
  while (rel >= JBT * (a + 1)) { rel -= JBT * (a + 1); ++a; }
  const int jt   = rel;
  const bool diag = (jt >= JBT * a);
  const int i0 = a * TI;
  const int j0 = jt * TJ;

  __shared__ float xs[TJ], ys[TJ], zs[TJ], sjs[TJ], ms[TJ];
  __shared__ float wsum[4];

  const float* qb = q + (size_t)b * N * 3;

  // Stage j tile raw coords + |qj|^2 + mass (SoA -> broadcast ds_read_b128).
  if (tid < TJ) {
    const int j = j0 + tid;
    const float x = qb[3 * j + 0];
    const float y = qb[3 * j + 1];
    const float z = qb[3 * j + 2];
    xs[tid]  = x;
    ys[tid]  = y;
    zs[tid]  = z;
    sjs[tid] = fmaf(x, x, fmaf(y, y, z * z));
    ms[tid]  = m[j];
  }

  // Per-thread i-slots: raw coords (diag path), -2*coords (expansion path),
  // se = |qi|^2 + eps, mass.
  float xi[IPT], yi[IPT], zi[IPT], txi[IPT], tyi[IPT], tzi[IPT], se[IPT], mi[IPT];
#pragma unroll
  for (int s = 0; s < IPT; ++s) {
    const int i = i0 + s * BLK + tid;
    xi[s] = qb[3 * i + 0];
    yi[s] = qb[3 * i + 1];
    zi[s] = qb[3 * i + 2];
    txi[s] = -2.f * xi[s];
    tyi[s] = -2.f * yi[s];
    tzi[s] = -2.f * zi[s];
    se[s] = fmaf(xi[s], xi[s], fmaf(yi[s], yi[s], fmaf(zi[s], zi[s], EPS_CONST)));
    mi[s] = m[i];
  }

  __syncthreads();

  float acc[IPT] = {};

  if (diag) {
    // Diff form: at i==j the fma chain yields r2 == EPS exactly; the self
    // contribution mi*rsq(EPS) is subtracted bit-exactly after the loop.
#pragma unroll 2
    for (int k = 0; k < TJ; k += 4) {
      const v4f xj = *(const v4f*)&xs[k];
      const v4f yj = *(const v4f*)&ys[k];
      const v4f zj = *(const v4f*)&zs[k];
      const v4f mj = *(const v4f*)&ms[k];
#pragma unroll
      for (int s = 0; s < IPT; ++s) {
#pragma unroll
        for (int u = 0; u < 4; ++u) {
          const float dx = xi[s] - xj[u];
          const float dy = yi[s] - yj[u];
          const float dz = zi[s] - zj[u];
          const float r2 = fmaf(dx, dx, fmaf(dy, dy, fmaf(dz, dz, EPS_CONST)));
          acc[s] = fmaf(mj[u], __builtin_amdgcn_rsqf(r2), acc[s]);
        }
      }
    }
  } else {
#pragma unroll 2
    for (int k = 0; k < TJ; k += 4) {
      const v4f xj = *(const v4f*)&xs[k];
      const v4f yj = *(const v4f*)&ys[k];
      const v4f zj = *(const v4f*)&zs[k];
      const v4f sj = *(const v4f*)&sjs[k];
      const v4f mj = *(const v4f*)&ms[k];
#pragma unroll
      for (int s = 0; s < IPT; ++s) {
#pragma unroll
        for (int u = 0; u < 4; ++u) {
          float t = se[s] + sj[u];
          t = fmaf(txi[s], xj[u], t);
          t = fmaf(tyi[s], yj[u], t);
          t = fmaf(tzi[s], zj[u], t);
          acc[s] = fmaf(mj[u], __builtin_amdgcn_rsqf(t), acc[s]);
        }
      }
    }
  }

  float tsum = 0.f;
#pragma unroll
  for (int s = 0; s < IPT; ++s) {
    const int i = i0 + s * BLK + tid;
    float h = acc[s];
    if (diag && i >= j0 && i < j0 + TJ) h -= mi[s] * __builtin_amdgcn_rsqf(EPS_CONST);
    tsum += mi[s] * h;
  }

  // Block reduction: 64-lane shuffle, then across 4 waves via LDS.
#pragma unroll
  for (int off = 32; off > 0; off >>= 1) tsum += __shfl_down(tsum, off);
  const int wid  = tid >> 6;
  const int lane = tid & 63;
  if (lane == 0) wsum[wid] = tsum;
  __syncthreads();
  if (tid == 0) {
    const float s = (wsum[0] + wsum[1]) + (wsum[2] + wsum[3]);
    // off-diag: each unordered pair once -> -G; diag: both orders -> -G/2.
    const float scale = diag ? (-0.5f * G_CONST) : (-G_CONST);
    atomicAdd(out + b, s * scale);
  }
}

extern "C" void kernel_launch(void* const* d_in, const int* in_sizes, int n_in,
                              void* d_out, int out_size, void* d_ws, size_t ws_size,
                              hipStream_t stream) {
  const float* q = (const float*)d_in[0];
  const float* m = (const float*)d_in[1];
  float* out = (float*)d_out;

  const int N = in_sizes[1];
  const int B = in_sizes[0] / (N * 3);

  hipMemsetAsync(out, 0, (size_t)out_size * sizeof(float), stream);

  const int nti = N / TI;                      // 4 i-tiles
  const int bpb = JBT * nti * (nti + 1) / 2;   // 160 blocks per batch
  dim3 grid(bpb, 1, B);                        // 1280 blocks = 5/CU exactly
  grav_kernel<<<grid, BLK, 0, stream>>>(q, m, out, N);
}